// Round 1
// baseline (1497.528 us; speedup 1.0000x reference)
//
#include <hip/hip_runtime.h>

// LightGCN: ego = concat(user_emb, item_emb); x=ego; acc=ego;
// 3x { x = spmm(adj, x); acc += x }; out = gather(acc/4) at users/items.
//
// Strategy: build CSR on device per call (hist -> scan -> scatter, int atomics
// only), then gather-formulation SpMM: one 64-lane wave per output row, lane =
// embedding dim. No f32 atomics anywhere. acc is only materialized at the 8192
// output rows (directly in d_out).
//
// Workspace layout (needs ~117 MB):
//   row_cnt[150000] | row_ptr[150000] | cursor[150000] | csr int2[4.8M] | x1 | x2

#define USERS_N 100000
#define ITEMS_N 50000
#define NODES_N 150000
#define EMB 64
#define NNZ_N 4800000
#define OUT_ROWS 8192

__global__ __launch_bounds__(256) void hist_kernel(const int* __restrict__ row,
                                                   int* __restrict__ cnt) {
    int i = blockIdx.x * 256 + threadIdx.x;
    if (i < NNZ_N) atomicAdd(&cnt[row[i]], 1);
}

// Single-block chunked exclusive scan of 150000 counts -> row_ptr and cursor.
__global__ __launch_bounds__(1024) void scan_kernel(const int* __restrict__ cnt,
                                                    int* __restrict__ row_ptr,
                                                    int* __restrict__ cursor) {
    __shared__ int sums[1024];
    const int CH = (NODES_N + 1023) / 1024;  // 147 elements per thread
    int t = threadIdx.x;
    int base = t * CH;
    int s = 0;
    for (int i = 0; i < CH; ++i) {
        int j = base + i;
        if (j < NODES_N) s += cnt[j];
    }
    sums[t] = s;
    __syncthreads();
    // Hillis-Steele inclusive scan over the 1024 per-thread sums.
    for (int off = 1; off < 1024; off <<= 1) {
        int v = (t >= off) ? sums[t - off] : 0;
        __syncthreads();
        sums[t] += v;
        __syncthreads();
    }
    int run = (t == 0) ? 0 : sums[t - 1];  // exclusive prefix for this chunk
    for (int i = 0; i < CH; ++i) {
        int j = base + i;
        if (j < NODES_N) {
            row_ptr[j] = run;
            cursor[j] = run;
            run += cnt[j];
        }
    }
}

__global__ __launch_bounds__(256) void scatter_kernel(const int* __restrict__ row,
                                                      const int* __restrict__ col,
                                                      const float* __restrict__ val,
                                                      int* __restrict__ cursor,
                                                      int2* __restrict__ csr) {
    int i = blockIdx.x * 256 + threadIdx.x;
    if (i < NNZ_N) {
        int r = row[i];
        int pos = atomicAdd(&cursor[r], 1);
        csr[pos] = make_int2(col[i], __float_as_int(val[i]));
    }
}

// One wave per output row; lane = embedding dim. 4-deep unroll to keep
// several independent gathers in flight per wave.
template <bool FIRST>
__global__ __launch_bounds__(256) void spmm_kernel(const int* __restrict__ row_ptr,
                                                   const int* __restrict__ row_cnt,
                                                   const int2* __restrict__ csr,
                                                   const float* __restrict__ ue,
                                                   const float* __restrict__ ie,
                                                   const float* __restrict__ xin,
                                                   float* __restrict__ xout) {
    int wave = (blockIdx.x * 256 + threadIdx.x) >> 6;
    int lane = threadIdx.x & 63;
    if (wave >= NODES_N) return;
    int start = row_ptr[wave];
    int n = row_cnt[wave];

    auto xld = [&](int c) -> float {
        if (FIRST) {
            // ego = concat(user_emb, item_emb); c is wave-uniform -> uniform branch
            return (c < USERS_N) ? ue[c * EMB + lane] : ie[(c - USERS_N) * EMB + lane];
        } else {
            return xin[c * EMB + lane];
        }
    };

    float acc = 0.0f;
    int e = start, end = start + n;
    for (; e + 4 <= end; e += 4) {
        int2 a = csr[e + 0];
        int2 b = csr[e + 1];
        int2 c = csr[e + 2];
        int2 d = csr[e + 3];
        float xa = xld(a.x);
        float xb = xld(b.x);
        float xc = xld(c.x);
        float xd = xld(d.x);
        acc += __int_as_float(a.y) * xa;
        acc += __int_as_float(b.y) * xb;
        acc += __int_as_float(c.y) * xc;
        acc += __int_as_float(d.y) * xd;
    }
    for (; e < end; ++e) {
        int2 a = csr[e];
        acc += __int_as_float(a.y) * xld(a.x);
    }
    xout[wave * EMB + lane] = acc;
}

// Accumulate 0.25 * layer_x at the 8192 gathered output rows.
template <bool INIT>
__global__ __launch_bounds__(256) void gather_kernel(const int* __restrict__ users,
                                                     const int* __restrict__ items,
                                                     const float* __restrict__ ue,
                                                     const float* __restrict__ ie,
                                                     const float* __restrict__ x,
                                                     float* __restrict__ out) {
    int o = (blockIdx.x * 256 + threadIdx.x) >> 6;
    int lane = threadIdx.x & 63;
    if (o >= OUT_ROWS) return;
    int node = (o < 4096) ? users[o] : (USERS_N + items[o - 4096]);
    if (INIT) {
        float v = (node < USERS_N) ? ue[node * EMB + lane]
                                   : ie[(node - USERS_N) * EMB + lane];
        out[o * EMB + lane] = 0.25f * v;  // full overwrite: initializes d_out
    } else {
        out[o * EMB + lane] += 0.25f * x[node * EMB + lane];
    }
}

extern "C" void kernel_launch(void* const* d_in, const int* in_sizes, int n_in,
                              void* d_out, int out_size, void* d_ws, size_t ws_size,
                              hipStream_t stream) {
    const float* ue   = (const float*)d_in[0];
    const float* ie   = (const float*)d_in[1];
    const int*   arow = (const int*)d_in[2];
    const int*   acol = (const int*)d_in[3];
    const float* aval = (const float*)d_in[4];
    const int*   users = (const int*)d_in[5];
    const int*   items = (const int*)d_in[6];
    float* out = (float*)d_out;

    char* w = (char*)d_ws;
    int* row_cnt = (int*)w;
    int* row_ptr = row_cnt + NODES_N;
    int* cursor  = row_ptr + NODES_N;
    size_t int_bytes = ((size_t)3 * NODES_N * sizeof(int) + 255) & ~(size_t)255;
    int2* csr = (int2*)(w + int_bytes);
    float* x1 = (float*)((char*)csr + (size_t)NNZ_N * sizeof(int2));
    float* x2 = x1 + (size_t)NODES_N * EMB;

    hipMemsetAsync(row_cnt, 0, NODES_N * sizeof(int), stream);
    hist_kernel<<<(NNZ_N + 255) / 256, 256, 0, stream>>>(arow, row_cnt);
    scan_kernel<<<1, 1024, 0, stream>>>(row_cnt, row_ptr, cursor);
    scatter_kernel<<<(NNZ_N + 255) / 256, 256, 0, stream>>>(arow, acol, aval, cursor, csr);

    const int SPMM_BLOCKS = NODES_N / 4;   // 4 waves/block, 1 row/wave
    const int GATH_BLOCKS = OUT_ROWS / 4;

    gather_kernel<true><<<GATH_BLOCKS, 256, 0, stream>>>(users, items, ue, ie, nullptr, out);
    spmm_kernel<true><<<SPMM_BLOCKS, 256, 0, stream>>>(row_ptr, row_cnt, csr, ue, ie, nullptr, x1);
    gather_kernel<false><<<GATH_BLOCKS, 256, 0, stream>>>(users, items, ue, ie, x1, out);
    spmm_kernel<false><<<SPMM_BLOCKS, 256, 0, stream>>>(row_ptr, row_cnt, csr, ue, ie, x1, x2);
    gather_kernel<false><<<GATH_BLOCKS, 256, 0, stream>>>(users, items, ue, ie, x2, out);
    spmm_kernel<false><<<SPMM_BLOCKS, 256, 0, stream>>>(row_ptr, row_cnt, csr, ue, ie, x2, x1);
    gather_kernel<false><<<GATH_BLOCKS, 256, 0, stream>>>(users, items, ue, ie, x1, out);
}

// Round 2
// 1120.221 us; speedup vs baseline: 1.3368x; 1.3368x over previous
//
#include <hip/hip_runtime.h>

// LightGCN: ego = concat(user_emb, item_emb); x=ego; acc=ego;
// 3x { x = spmm(adj, x); acc += x }; out = gather(acc/4) at users/items.
//
// R1: replaced 400us single-block scan with 3-kernel multi-block scan
// (reduce -> scan block sums -> apply). Everything else unchanged.
//
// Workspace layout (~117 MB):
//   row_cnt[150000] | row_ptr[150000] | cursor[150000] | blk_sum[256] |
//   blk_off[256] | csr int2[4.8M] | x1 | x2

#define USERS_N 100000
#define ITEMS_N 50000
#define NODES_N 150000
#define EMB 64
#define NNZ_N 4800000
#define OUT_ROWS 8192

#define SCAN_BLK 147           // ceil(150000/1024)
#define SCAN_CHUNK 1024        // elements per block
#define SCAN_T 256             // threads per scan block (4 elem/thread)

__global__ __launch_bounds__(256) void hist_kernel(const int* __restrict__ row,
                                                   int* __restrict__ cnt) {
    int i = blockIdx.x * 256 + threadIdx.x;
    if (i < NNZ_N) atomicAdd(&cnt[row[i]], 1);
}

// --- multi-block exclusive scan of cnt[150000] -> row_ptr, cursor ---

__global__ __launch_bounds__(SCAN_T) void scan_reduce_kernel(const int* __restrict__ cnt,
                                                             int* __restrict__ blk_sum) {
    __shared__ int lds[SCAN_T / 64];
    int t = threadIdx.x;
    int base = blockIdx.x * SCAN_CHUNK + t * 4;
    int s = 0;
#pragma unroll
    for (int i = 0; i < 4; ++i) {
        int j = base + i;
        if (j < NODES_N) s += cnt[j];
    }
    // wave reduce
    for (int off = 32; off > 0; off >>= 1) s += __shfl_down(s, off);
    if ((t & 63) == 0) lds[t >> 6] = s;
    __syncthreads();
    if (t == 0) {
        int tot = 0;
#pragma unroll
        for (int w = 0; w < SCAN_T / 64; ++w) tot += lds[w];
        blk_sum[blockIdx.x] = tot;
    }
}

__global__ __launch_bounds__(256) void scan_sums_kernel(const int* __restrict__ blk_sum,
                                                        int* __restrict__ blk_off) {
    __shared__ int lds[256];
    int t = threadIdx.x;
    lds[t] = (t < SCAN_BLK) ? blk_sum[t] : 0;
    __syncthreads();
    for (int off = 1; off < 256; off <<= 1) {
        int v = (t >= off) ? lds[t - off] : 0;
        __syncthreads();
        lds[t] += v;
        __syncthreads();
    }
    if (t < SCAN_BLK) blk_off[t] = (t == 0) ? 0 : lds[t - 1];  // exclusive
}

__global__ __launch_bounds__(SCAN_T) void scan_apply_kernel(const int* __restrict__ cnt,
                                                            const int* __restrict__ blk_off,
                                                            int* __restrict__ row_ptr,
                                                            int* __restrict__ cursor) {
    __shared__ int lds[SCAN_T];
    int t = threadIdx.x;
    int base = blockIdx.x * SCAN_CHUNK + t * 4;
    int c0 = 0, c1 = 0, c2 = 0, c3 = 0;
    if (base + 0 < NODES_N) c0 = cnt[base + 0];
    if (base + 1 < NODES_N) c1 = cnt[base + 1];
    if (base + 2 < NODES_N) c2 = cnt[base + 2];
    if (base + 3 < NODES_N) c3 = cnt[base + 3];
    int local = c0 + c1 + c2 + c3;
    lds[t] = local;
    __syncthreads();
    for (int off = 1; off < SCAN_T; off <<= 1) {
        int v = (t >= off) ? lds[t - off] : 0;
        __syncthreads();
        lds[t] += v;
        __syncthreads();
    }
    int run = lds[t] - local + blk_off[blockIdx.x];  // exclusive prefix for elem 0
    int j = base;
    if (j < NODES_N) { row_ptr[j] = run; cursor[j] = run; run += c0; } ++j;
    if (j < NODES_N) { row_ptr[j] = run; cursor[j] = run; run += c1; } ++j;
    if (j < NODES_N) { row_ptr[j] = run; cursor[j] = run; run += c2; } ++j;
    if (j < NODES_N) { row_ptr[j] = run; cursor[j] = run; }
}

// --- CSR scatter ---

__global__ __launch_bounds__(256) void scatter_kernel(const int* __restrict__ row,
                                                      const int* __restrict__ col,
                                                      const float* __restrict__ val,
                                                      int* __restrict__ cursor,
                                                      int2* __restrict__ csr) {
    int i = blockIdx.x * 256 + threadIdx.x;
    if (i < NNZ_N) {
        int r = row[i];
        int pos = atomicAdd(&cursor[r], 1);
        csr[pos] = make_int2(col[i], __float_as_int(val[i]));
    }
}

// --- SpMM: one wave per output row; lane = embedding dim ---

template <bool FIRST>
__global__ __launch_bounds__(256) void spmm_kernel(const int* __restrict__ row_ptr,
                                                   const int* __restrict__ row_cnt,
                                                   const int2* __restrict__ csr,
                                                   const float* __restrict__ ue,
                                                   const float* __restrict__ ie,
                                                   const float* __restrict__ xin,
                                                   float* __restrict__ xout) {
    int wave = (blockIdx.x * 256 + threadIdx.x) >> 6;
    int lane = threadIdx.x & 63;
    if (wave >= NODES_N) return;
    int start = row_ptr[wave];
    int n = row_cnt[wave];

    auto xld = [&](int c) -> float {
        if (FIRST) {
            return (c < USERS_N) ? ue[c * EMB + lane] : ie[(c - USERS_N) * EMB + lane];
        } else {
            return xin[c * EMB + lane];
        }
    };

    float acc = 0.0f;
    int e = start, end = start + n;
    for (; e + 4 <= end; e += 4) {
        int2 a = csr[e + 0];
        int2 b = csr[e + 1];
        int2 c = csr[e + 2];
        int2 d = csr[e + 3];
        float xa = xld(a.x);
        float xb = xld(b.x);
        float xc = xld(c.x);
        float xd = xld(d.x);
        acc += __int_as_float(a.y) * xa;
        acc += __int_as_float(b.y) * xb;
        acc += __int_as_float(c.y) * xc;
        acc += __int_as_float(d.y) * xd;
    }
    for (; e < end; ++e) {
        int2 a = csr[e];
        acc += __int_as_float(a.y) * xld(a.x);
    }
    xout[wave * EMB + lane] = acc;
}

// --- accumulate 0.25 * layer_x at the 8192 output rows ---

template <bool INIT>
__global__ __launch_bounds__(256) void gather_kernel(const int* __restrict__ users,
                                                     const int* __restrict__ items,
                                                     const float* __restrict__ ue,
                                                     const float* __restrict__ ie,
                                                     const float* __restrict__ x,
                                                     float* __restrict__ out) {
    int o = (blockIdx.x * 256 + threadIdx.x) >> 6;
    int lane = threadIdx.x & 63;
    if (o >= OUT_ROWS) return;
    int node = (o < 4096) ? users[o] : (USERS_N + items[o - 4096]);
    if (INIT) {
        float v = (node < USERS_N) ? ue[node * EMB + lane]
                                   : ie[(node - USERS_N) * EMB + lane];
        out[o * EMB + lane] = 0.25f * v;
    } else {
        out[o * EMB + lane] += 0.25f * x[node * EMB + lane];
    }
}

extern "C" void kernel_launch(void* const* d_in, const int* in_sizes, int n_in,
                              void* d_out, int out_size, void* d_ws, size_t ws_size,
                              hipStream_t stream) {
    const float* ue   = (const float*)d_in[0];
    const float* ie   = (const float*)d_in[1];
    const int*   arow = (const int*)d_in[2];
    const int*   acol = (const int*)d_in[3];
    const float* aval = (const float*)d_in[4];
    const int*   users = (const int*)d_in[5];
    const int*   items = (const int*)d_in[6];
    float* out = (float*)d_out;

    char* w = (char*)d_ws;
    int* row_cnt = (int*)w;
    int* row_ptr = row_cnt + NODES_N;
    int* cursor  = row_ptr + NODES_N;
    int* blk_sum = cursor + NODES_N;
    int* blk_off = blk_sum + 256;
    size_t int_bytes = ((size_t)(3 * NODES_N + 512) * sizeof(int) + 255) & ~(size_t)255;
    int2* csr = (int2*)(w + int_bytes);
    float* x1 = (float*)((char*)csr + (size_t)NNZ_N * sizeof(int2));
    float* x2 = x1 + (size_t)NODES_N * EMB;

    hipMemsetAsync(row_cnt, 0, NODES_N * sizeof(int), stream);
    hist_kernel<<<(NNZ_N + 255) / 256, 256, 0, stream>>>(arow, row_cnt);
    scan_reduce_kernel<<<SCAN_BLK, SCAN_T, 0, stream>>>(row_cnt, blk_sum);
    scan_sums_kernel<<<1, 256, 0, stream>>>(blk_sum, blk_off);
    scan_apply_kernel<<<SCAN_BLK, SCAN_T, 0, stream>>>(row_cnt, blk_off, row_ptr, cursor);
    scatter_kernel<<<(NNZ_N + 255) / 256, 256, 0, stream>>>(arow, acol, aval, cursor, csr);

    const int SPMM_BLOCKS = (NODES_N + 3) / 4;   // 4 waves/block, 1 row/wave
    const int GATH_BLOCKS = OUT_ROWS / 4;

    gather_kernel<true><<<GATH_BLOCKS, 256, 0, stream>>>(users, items, ue, ie, nullptr, out);
    spmm_kernel<true><<<SPMM_BLOCKS, 256, 0, stream>>>(row_ptr, row_cnt, csr, ue, ie, nullptr, x1);
    gather_kernel<false><<<GATH_BLOCKS, 256, 0, stream>>>(users, items, ue, ie, x1, out);
    spmm_kernel<false><<<SPMM_BLOCKS, 256, 0, stream>>>(row_ptr, row_cnt, csr, ue, ie, x1, x2);
    gather_kernel<false><<<GATH_BLOCKS, 256, 0, stream>>>(users, items, ue, ie, x2, out);
    spmm_kernel<false><<<SPMM_BLOCKS, 256, 0, stream>>>(row_ptr, row_cnt, csr, ue, ie, x2, x1);
    gather_kernel<false><<<GATH_BLOCKS, 256, 0, stream>>>(users, items, ue, ie, x1, out);
}

// Round 3
// 968.543 us; speedup vs baseline: 1.5462x; 1.1566x over previous
//
#include <hip/hip_runtime.h>

// LightGCN: ego = concat(user_emb, item_emb); x=ego; acc=ego;
// 3x { x = spmm(adj, x); acc += x }; out = gather(acc/4) at users/items.
//
// R2: replaced one-pass atomic-cursor CSR scatter (389us, 296MB WRITE_SIZE due
// to 150K random write frontiers thrashing L2) with a two-phase binned build:
//   bin_kernel: LDS histogram over 586 row-buckets (row>>8), reserve ranges
//     with one global atomic per (wg,bucket), write SoA (row,col,val) to
//     bucket-contiguous regions (586 active frontiers = 37KB, cache-resident).
//   bucket_scatter_kernel: one wg per bucket, LDS cursors for its 256 rows,
//     scatter (col,val) into the bucket's ~64KB CSR window.
// Bucket bases are row_ptr[b<<8] (free from the scan). Bin arrays overlay the
// x1/x2 region (dead until SpMM). SpMM unchanged this round.

#define USERS_N 100000
#define ITEMS_N 50000
#define NODES_N 150000
#define EMB 64
#define NNZ_N 4800000
#define OUT_ROWS 8192

#define SCAN_BLK 147           // ceil(150000/1024)
#define SCAN_CHUNK 1024        // elements per block
#define SCAN_T 256             // threads per scan block (4 elem/thread)

#define NB 586                 // ceil(150000/256) row-buckets
#define P1_CHUNK 16            // edges per thread in bin_kernel
#define P1_EDGES (256 * P1_CHUNK)

__global__ __launch_bounds__(256) void hist_kernel(const int* __restrict__ row,
                                                   int* __restrict__ cnt) {
    int i = blockIdx.x * 256 + threadIdx.x;
    if (i < NNZ_N) atomicAdd(&cnt[row[i]], 1);
}

// --- multi-block exclusive scan of cnt[150000] -> row_ptr ---

__global__ __launch_bounds__(SCAN_T) void scan_reduce_kernel(const int* __restrict__ cnt,
                                                             int* __restrict__ blk_sum) {
    __shared__ int lds[SCAN_T / 64];
    int t = threadIdx.x;
    int base = blockIdx.x * SCAN_CHUNK + t * 4;
    int s = 0;
#pragma unroll
    for (int i = 0; i < 4; ++i) {
        int j = base + i;
        if (j < NODES_N) s += cnt[j];
    }
    for (int off = 32; off > 0; off >>= 1) s += __shfl_down(s, off);
    if ((t & 63) == 0) lds[t >> 6] = s;
    __syncthreads();
    if (t == 0) {
        int tot = 0;
#pragma unroll
        for (int w = 0; w < SCAN_T / 64; ++w) tot += lds[w];
        blk_sum[blockIdx.x] = tot;
    }
}

__global__ __launch_bounds__(256) void scan_sums_kernel(const int* __restrict__ blk_sum,
                                                        int* __restrict__ blk_off) {
    __shared__ int lds[256];
    int t = threadIdx.x;
    lds[t] = (t < SCAN_BLK) ? blk_sum[t] : 0;
    __syncthreads();
    for (int off = 1; off < 256; off <<= 1) {
        int v = (t >= off) ? lds[t - off] : 0;
        __syncthreads();
        lds[t] += v;
        __syncthreads();
    }
    if (t < SCAN_BLK) blk_off[t] = (t == 0) ? 0 : lds[t - 1];  // exclusive
}

__global__ __launch_bounds__(SCAN_T) void scan_apply_kernel(const int* __restrict__ cnt,
                                                            const int* __restrict__ blk_off,
                                                            int* __restrict__ row_ptr) {
    __shared__ int lds[SCAN_T];
    int t = threadIdx.x;
    int base = blockIdx.x * SCAN_CHUNK + t * 4;
    int c0 = 0, c1 = 0, c2 = 0, c3 = 0;
    if (base + 0 < NODES_N) c0 = cnt[base + 0];
    if (base + 1 < NODES_N) c1 = cnt[base + 1];
    if (base + 2 < NODES_N) c2 = cnt[base + 2];
    if (base + 3 < NODES_N) c3 = cnt[base + 3];
    int local = c0 + c1 + c2 + c3;
    lds[t] = local;
    __syncthreads();
    for (int off = 1; off < SCAN_T; off <<= 1) {
        int v = (t >= off) ? lds[t - off] : 0;
        __syncthreads();
        lds[t] += v;
        __syncthreads();
    }
    int run = lds[t] - local + blk_off[blockIdx.x];
    int j = base;
    if (j < NODES_N) { row_ptr[j] = run; run += c0; } ++j;
    if (j < NODES_N) { row_ptr[j] = run; run += c1; } ++j;
    if (j < NODES_N) { row_ptr[j] = run; run += c2; } ++j;
    if (j < NODES_N) { row_ptr[j] = run; }
}

// --- binned CSR build ---

__global__ __launch_bounds__(256) void init_gcur_kernel(const int* __restrict__ row_ptr,
                                                        int* __restrict__ gcur) {
    int b = blockIdx.x * 256 + threadIdx.x;
    if (b < NB) gcur[b] = row_ptr[b << 8];
}

__global__ __launch_bounds__(256) void bin_kernel(const int* __restrict__ row,
                                                  const int* __restrict__ col,
                                                  const float* __restrict__ val,
                                                  int* __restrict__ gcur,
                                                  int* __restrict__ brow,
                                                  int* __restrict__ bcol,
                                                  float* __restrict__ bval) {
    __shared__ int lhist[NB];
    __shared__ int lbase[NB];
    int t = threadIdx.x;
    for (int b = t; b < NB; b += 256) lhist[b] = 0;
    __syncthreads();
    long base = (long)blockIdx.x * P1_EDGES;
    int r[P1_CHUNK];
#pragma unroll
    for (int i = 0; i < P1_CHUNK; ++i) {
        long e = base + t + i * 256;  // coalesced
        r[i] = (e < NNZ_N) ? row[e] : -1;
        if (r[i] >= 0) atomicAdd(&lhist[r[i] >> 8], 1);
    }
    __syncthreads();
    for (int b = t; b < NB; b += 256) {
        lbase[b] = atomicAdd(&gcur[b], lhist[b]);
        lhist[b] = 0;
    }
    __syncthreads();
#pragma unroll
    for (int i = 0; i < P1_CHUNK; ++i) {
        if (r[i] >= 0) {
            long e = base + t + i * 256;
            int b = r[i] >> 8;
            int pos = lbase[b] + atomicAdd(&lhist[b], 1);
            brow[pos] = r[i];
            bcol[pos] = col[e];
            bval[pos] = val[e];
        }
    }
}

__global__ __launch_bounds__(256) void bucket_scatter_kernel(const int* __restrict__ row_ptr,
                                                             const int* __restrict__ brow,
                                                             const int* __restrict__ bcol,
                                                             const float* __restrict__ bval,
                                                             int2* __restrict__ csr) {
    __shared__ int cur[256];
    int b = blockIdx.x;
    int rowbase = b << 8;
    int t = threadIdx.x;
    int start = row_ptr[rowbase];
    int end = (rowbase + 256 >= NODES_N) ? NNZ_N : row_ptr[rowbase + 256];
    if (rowbase + t < NODES_N) cur[t] = row_ptr[rowbase + t];
    __syncthreads();
    for (int i = start + t; i < end; i += 256) {
        int r = brow[i] - rowbase;
        int p = atomicAdd(&cur[r], 1);
        csr[p] = make_int2(bcol[i], __float_as_int(bval[i]));
    }
}

// --- SpMM: one wave per output row; lane = embedding dim ---

template <bool FIRST>
__global__ __launch_bounds__(256) void spmm_kernel(const int* __restrict__ row_ptr,
                                                   const int* __restrict__ row_cnt,
                                                   const int2* __restrict__ csr,
                                                   const float* __restrict__ ue,
                                                   const float* __restrict__ ie,
                                                   const float* __restrict__ xin,
                                                   float* __restrict__ xout) {
    int wave = (blockIdx.x * 256 + threadIdx.x) >> 6;
    int lane = threadIdx.x & 63;
    if (wave >= NODES_N) return;
    int start = row_ptr[wave];
    int n = row_cnt[wave];

    auto xld = [&](int c) -> float {
        if (FIRST) {
            return (c < USERS_N) ? ue[c * EMB + lane] : ie[(c - USERS_N) * EMB + lane];
        } else {
            return xin[c * EMB + lane];
        }
    };

    float acc = 0.0f;
    int e = start, end = start + n;
    for (; e + 4 <= end; e += 4) {
        int2 a = csr[e + 0];
        int2 b = csr[e + 1];
        int2 c = csr[e + 2];
        int2 d = csr[e + 3];
        float xa = xld(a.x);
        float xb = xld(b.x);
        float xc = xld(c.x);
        float xd = xld(d.x);
        acc += __int_as_float(a.y) * xa;
        acc += __int_as_float(b.y) * xb;
        acc += __int_as_float(c.y) * xc;
        acc += __int_as_float(d.y) * xd;
    }
    for (; e < end; ++e) {
        int2 a = csr[e];
        acc += __int_as_float(a.y) * xld(a.x);
    }
    xout[wave * EMB + lane] = acc;
}

// --- accumulate 0.25 * layer_x at the 8192 output rows ---

template <bool INIT>
__global__ __launch_bounds__(256) void gather_kernel(const int* __restrict__ users,
                                                     const int* __restrict__ items,
                                                     const float* __restrict__ ue,
                                                     const float* __restrict__ ie,
                                                     const float* __restrict__ x,
                                                     float* __restrict__ out) {
    int o = (blockIdx.x * 256 + threadIdx.x) >> 6;
    int lane = threadIdx.x & 63;
    if (o >= OUT_ROWS) return;
    int node = (o < 4096) ? users[o] : (USERS_N + items[o - 4096]);
    if (INIT) {
        float v = (node < USERS_N) ? ue[node * EMB + lane]
                                   : ie[(node - USERS_N) * EMB + lane];
        out[o * EMB + lane] = 0.25f * v;
    } else {
        out[o * EMB + lane] += 0.25f * x[node * EMB + lane];
    }
}

extern "C" void kernel_launch(void* const* d_in, const int* in_sizes, int n_in,
                              void* d_out, int out_size, void* d_ws, size_t ws_size,
                              hipStream_t stream) {
    const float* ue   = (const float*)d_in[0];
    const float* ie   = (const float*)d_in[1];
    const int*   arow = (const int*)d_in[2];
    const int*   acol = (const int*)d_in[3];
    const float* aval = (const float*)d_in[4];
    const int*   users = (const int*)d_in[5];
    const int*   items = (const int*)d_in[6];
    float* out = (float*)d_out;

    char* w = (char*)d_ws;
    int* row_cnt = (int*)w;
    int* row_ptr = row_cnt + NODES_N;
    int* gcur    = row_ptr + NODES_N;
    int* blk_sum = gcur + ((NB + 63) & ~63);
    int* blk_off = blk_sum + 256;
    size_t int_bytes = ((size_t)(2 * NODES_N + 1024 + 512) * sizeof(int) + 255) & ~(size_t)255;
    int2* csr = (int2*)(w + int_bytes);
    float* x1 = (float*)((char*)csr + (size_t)NNZ_N * sizeof(int2));
    float* x2 = x1 + (size_t)NODES_N * EMB;
    // bin arrays overlay x1/x2 (57.6MB <= 76.8MB); dead before first spmm write
    int*   brow = (int*)x1;
    int*   bcol = brow + NNZ_N;
    float* bval = (float*)(bcol + NNZ_N);

    hipMemsetAsync(row_cnt, 0, NODES_N * sizeof(int), stream);
    hist_kernel<<<(NNZ_N + 255) / 256, 256, 0, stream>>>(arow, row_cnt);
    scan_reduce_kernel<<<SCAN_BLK, SCAN_T, 0, stream>>>(row_cnt, blk_sum);
    scan_sums_kernel<<<1, 256, 0, stream>>>(blk_sum, blk_off);
    scan_apply_kernel<<<SCAN_BLK, SCAN_T, 0, stream>>>(row_cnt, blk_off, row_ptr);
    init_gcur_kernel<<<(NB + 255) / 256, 256, 0, stream>>>(row_ptr, gcur);
    bin_kernel<<<(NNZ_N + P1_EDGES - 1) / P1_EDGES, 256, 0, stream>>>(
        arow, acol, aval, gcur, brow, bcol, bval);
    bucket_scatter_kernel<<<NB, 256, 0, stream>>>(row_ptr, brow, bcol, bval, csr);

    const int SPMM_BLOCKS = (NODES_N + 3) / 4;   // 4 waves/block, 1 row/wave
    const int GATH_BLOCKS = OUT_ROWS / 4;

    gather_kernel<true><<<GATH_BLOCKS, 256, 0, stream>>>(users, items, ue, ie, nullptr, out);
    spmm_kernel<true><<<SPMM_BLOCKS, 256, 0, stream>>>(row_ptr, row_cnt, csr, ue, ie, nullptr, x1);
    gather_kernel<false><<<GATH_BLOCKS, 256, 0, stream>>>(users, items, ue, ie, x1, out);
    spmm_kernel<false><<<SPMM_BLOCKS, 256, 0, stream>>>(row_ptr, row_cnt, csr, ue, ie, x1, x2);
    gather_kernel<false><<<GATH_BLOCKS, 256, 0, stream>>>(users, items, ue, ie, x2, out);
    spmm_kernel<false><<<SPMM_BLOCKS, 256, 0, stream>>>(row_ptr, row_cnt, csr, ue, ie, x2, x1);
    gather_kernel<false><<<GATH_BLOCKS, 256, 0, stream>>>(users, items, ue, ie, x1, out);
}